// Round 6
// baseline (369.175 us; speedup 1.0000x reference)
//
#include <hip/hip_runtime.h>

// Stream compaction via slice-binning (R6).
//   mask[i] = accept_index[i] >= 0 ; dst = excl-scan(mask)
//   out[dst[i]] = src[accept_index[i]] ; out[total..N) = 0
//
// R1-R5 evidence: random 64B line fills cap at ~3.5 TB/s on the L2-miss path
// regardless of L3/HBM service; without cross-block exchange, per-XCD reuse
// caps at 1.43 gathers/line. R6 bins table indices into 16 x 4MB slices so
// the gather phase runs one slice per XCD at a time (XCD-affine mapping,
// 2 blocks/CU) -> gathers hit the 4MB per-XCD L2. All other phases stream.
//
// Pipeline: K1 count -> K2 scan -> K3 bin -> K4 gather -> K5 emit -> K6 tail.
// Falls back to the R5 single-kernel path if ws_size < ~135 MB.

#define N_TOTAL  16777216
#define BLOCK    256
#define EPT2     32
#define TILE2    (BLOCK * EPT2)        // 8192
#define NB2      (N_TOTAL / TILE2)     // 2048
#define SLICE_LG 20                    // 2^20 elements = 4 MB slice
#define SLICES   16

// fallback (R5) tiling
#define EPT      16
#define TILE     (BLOCK * EPT)         // 4096
#define NBLOCKS  (N_TOTAL / TILE)      // 4096
#define SLICE_LG5 22
#define SLICES5  (N_TOTAL >> SLICE_LG5)

typedef float vfloat4 __attribute__((ext_vector_type(4)));

// ======================= K1: per-block per-slice counts =======================
__global__ __launch_bounds__(BLOCK) void k_count(const int* __restrict__ idx,
                                                 int* __restrict__ cnt) {
    __shared__ int h[SLICES];
    const int b = blockIdx.x, t = threadIdx.x;
    if (t < SLICES) h[t] = 0;
    __syncthreads();
    const int4* p = (const int4*)(idx + (size_t)b * TILE2 + (size_t)t * EPT2);
    int v[EPT2];
#pragma unroll
    for (int j = 0; j < EPT2 / 4; ++j) {
        int4 q = p[j];
        v[4*j+0]=q.x; v[4*j+1]=q.y; v[4*j+2]=q.z; v[4*j+3]=q.w;
    }
#pragma unroll
    for (int j = 0; j < EPT2; ++j) {
        unsigned s = (unsigned)v[j] >> SLICE_LG;
        if (s < SLICES) atomicAdd(&h[s], 1);
    }
    __syncthreads();
    if (t < SLICES) cnt[b * SLICES + t] = h[t];
}

// ======================= K2: scan (dest offsets + slice-column offsets) =======================
// cnt[NB2][16] -> off[NB2][16] (exclusive within each slice column),
// sliceBase[17], blockOff[NB2+1] (blockOff[NB2] = grand total).
__global__ __launch_bounds__(BLOCK) void k_scan2(const int* __restrict__ cnt,
                                                 int* __restrict__ off,
                                                 int* __restrict__ sliceBase,
                                                 int* __restrict__ blockOff) {
    const int t = threadIdx.x, lane = t & 63, wave = t >> 6;
    const int R = NB2 / BLOCK;   // 8 rows per thread, contiguous
    int sum[SLICES];
#pragma unroll
    for (int s = 0; s < SLICES; ++s) sum[s] = 0;
    for (int r = 0; r < R; ++r) {
        const int4* row = (const int4*)(cnt + (size_t)(t * R + r) * SLICES);
        int4 c0 = row[0], c1 = row[1], c2 = row[2], c3 = row[3];
        sum[0]+=c0.x; sum[1]+=c0.y; sum[2]+=c0.z; sum[3]+=c0.w;
        sum[4]+=c1.x; sum[5]+=c1.y; sum[6]+=c1.z; sum[7]+=c1.w;
        sum[8]+=c2.x; sum[9]+=c2.y; sum[10]+=c2.z; sum[11]+=c2.w;
        sum[12]+=c3.x; sum[13]+=c3.y; sum[14]+=c3.z; sum[15]+=c3.w;
    }
    int inc[SLICES];
#pragma unroll
    for (int s = 0; s < SLICES; ++s) inc[s] = sum[s];
#pragma unroll
    for (int d = 1; d < 64; d <<= 1) {
#pragma unroll
        for (int s = 0; s < SLICES; ++s) {
            int u = __shfl_up(inc[s], d);
            if (lane >= d) inc[s] += u;
        }
    }
    int tTot = 0;
#pragma unroll
    for (int s = 0; s < SLICES; ++s) tTot += sum[s];
    int tInc = tTot;
#pragma unroll
    for (int d = 1; d < 64; d <<= 1) {
        int u = __shfl_up(tInc, d);
        if (lane >= d) tInc += u;
    }
    __shared__ int wtot[4][SLICES], wstot[4];
    __shared__ int wbase[4][SLICES], wsbase[4];
    if (lane == 63) {
#pragma unroll
        for (int s = 0; s < SLICES; ++s) wtot[wave][s] = inc[s];
        wstot[wave] = tInc;
    }
    __syncthreads();
    if (t == 0) {
        int run[SLICES];
#pragma unroll
        for (int s = 0; s < SLICES; ++s) run[s] = 0;
        for (int w = 0; w < 4; ++w)
#pragma unroll
            for (int s = 0; s < SLICES; ++s) { wbase[w][s] = run[s]; run[s] += wtot[w][s]; }
        int sr = 0;
#pragma unroll
        for (int s = 0; s < SLICES; ++s) { sliceBase[s] = sr; sr += run[s]; }
        sliceBase[SLICES] = sr;
        blockOff[NB2] = sr;
        int rs = 0;
        for (int w = 0; w < 4; ++w) { wsbase[w] = rs; rs += wstot[w]; }
    }
    __syncthreads();
    int ex[SLICES];
#pragma unroll
    for (int s = 0; s < SLICES; ++s) ex[s] = inc[s] - sum[s] + wbase[wave][s];
    int exA = tInc - tTot + wsbase[wave];
    for (int r = 0; r < R; ++r) {
        const int b = t * R + r;
        blockOff[b] = exA;
        const int4* row = (const int4*)(cnt + (size_t)b * SLICES);
        int4 c0 = row[0], c1 = row[1], c2 = row[2], c3 = row[3];
        int rv[SLICES] = {c0.x,c0.y,c0.z,c0.w, c1.x,c1.y,c1.z,c1.w,
                          c2.x,c2.y,c2.z,c2.w, c3.x,c3.y,c3.z,c3.w};
#pragma unroll
        for (int s = 0; s < SLICES; ++s) {
            off[(size_t)b * SLICES + s] = ex[s];
            ex[s] += rv[s];
            exA   += rv[s];
        }
    }
}

// ======================= K3: bin table-indices by slice =======================
__global__ __launch_bounds__(BLOCK) void k_bin(const int* __restrict__ idx,
                                               const int* __restrict__ off,
                                               const int* __restrict__ sliceBase,
                                               int* __restrict__ bins) {
    const int b = blockIdx.x, t = threadIdx.x, lane = t & 63, wave = t >> 6;
    const int4* p = (const int4*)(idx + (size_t)b * TILE2 + (size_t)t * EPT2);
    int v[EPT2];
#pragma unroll
    for (int j = 0; j < EPT2 / 4; ++j) {
        int4 q = p[j];
        v[4*j+0]=q.x; v[4*j+1]=q.y; v[4*j+2]=q.z; v[4*j+3]=q.w;
    }
    int tc[SLICES];
#pragma unroll
    for (int s = 0; s < SLICES; ++s) tc[s] = 0;
#pragma unroll
    for (int j = 0; j < EPT2; ++j) {
        unsigned s = (unsigned)v[j] >> SLICE_LG;
#pragma unroll
        for (int s2 = 0; s2 < SLICES; ++s2) tc[s2] += (s == (unsigned)s2);
    }
    int inc[SLICES];
#pragma unroll
    for (int s = 0; s < SLICES; ++s) inc[s] = tc[s];
#pragma unroll
    for (int d = 1; d < 64; d <<= 1) {
#pragma unroll
        for (int s = 0; s < SLICES; ++s) {
            int u = __shfl_up(inc[s], d);
            if (lane >= d) inc[s] += u;
        }
    }
    __shared__ int wtot[4][SLICES], wbase[4][SLICES];
    __shared__ int gbase[SLICES], segStart[SLICES + 1];
    if (lane == 63)
#pragma unroll
        for (int s = 0; s < SLICES; ++s) wtot[wave][s] = inc[s];
    __syncthreads();
    if (t == 0) {
        int run[SLICES];
#pragma unroll
        for (int s = 0; s < SLICES; ++s) run[s] = 0;
        for (int w = 0; w < 4; ++w)
#pragma unroll
            for (int s = 0; s < SLICES; ++s) { wbase[w][s] = run[s]; run[s] += wtot[w][s]; }
        int sr = 0;
#pragma unroll
        for (int s = 0; s < SLICES; ++s) { segStart[s] = sr; sr += run[s]; }
        segStart[SLICES] = sr;
#pragma unroll
        for (int s = 0; s < SLICES; ++s)
            gbase[s] = sliceBase[s] + off[(size_t)b * SLICES + s] - segStart[s];
    }
    __syncthreads();
    __shared__ int exb[BLOCK][SLICES + 1];   // +1 pad vs 32 banks
    __shared__ int binsBuf[TILE2];
#pragma unroll
    for (int s = 0; s < SLICES; ++s)
        exb[t][s] = segStart[s] + (inc[s] - tc[s]) + wbase[wave][s];
#pragma unroll
    for (int j = 0; j < EPT2; ++j) {
        unsigned s = (unsigned)v[j] >> SLICE_LG;
        if (s < SLICES) {
            int pLoc = exb[t][s]++;
            binsBuf[pLoc] = v[j];
        }
    }
    __syncthreads();
    const int tot = segStart[SLICES];
    for (int k = t; k < tot; k += BLOCK) {
        int x = binsBuf[k];
        int s = 0;
#pragma unroll
        for (int q = 1; q < SLICES; ++q) s += (k >= segStart[q]);
        __builtin_nontemporal_store(x, bins + gbase[s] + k);
    }
}

// ======================= K4: per-slice dense gather =======================
// XCD-affine: blockIdx%8 -> XCD (round-robin dispatch heuristic, speed-only).
// 2048 blocks, forced 2 blocks/CU (72KB LDS pad) -> 512 resident = 1
// generation; XCD x works slice 2x+(gen>>1): live working set 4MB = its L2.
__global__ __launch_bounds__(BLOCK) void k_gather(const int* __restrict__ bins,
                                                  const float* __restrict__ src,
                                                  const int* __restrict__ sliceBase,
                                                  float* __restrict__ val) {
    __shared__ int pad[18432];   // 72 KB -> 2 blocks/CU
    const int t = threadIdx.x;
    pad[t] = t;
    const int n = blockIdx.x;
    const int x = n & 7;            // hoped XCD
    const int g = n >> 9;           // generation 0..3
    const int q = (n >> 3) & 63;    // rank within XCD within generation
    const int s = 2 * x + (g >> 1);
    const int c = (g & 1) * 64 + q; // chunk 0..127
    const int s0 = sliceBase[s], s1 = sliceBase[s + 1];
    if (s1 == -1) val[0] = (float)pad[t];   // never true; keeps pad alive
    const int len = s1 - s0;
    const int L = (len + 127) >> 7;
    const int start = s0 + c * L;
    const int end = (start + L < s1) ? (start + L) : s1;
    for (int k0 = start + t; k0 < end; k0 += BLOCK * 8) {
        int kk[8], bm[8];
        float fm[8];
#pragma unroll
        for (int m = 0; m < 8; ++m) kk[m] = k0 + m * BLOCK;
#pragma unroll
        for (int m = 0; m < 8; ++m) {
            int kc = kk[m] < end ? kk[m] : end - 1;
            bm[m] = __builtin_nontemporal_load(bins + kc);   // bins: stream once
        }
#pragma unroll
        for (int m = 0; m < 8; ++m) fm[m] = src[bm[m]];      // L2-resident slice
#pragma unroll
        for (int m = 0; m < 8; ++m)
            if (kk[m] < end) __builtin_nontemporal_store(fm[m], val + kk[m]);
    }
}

// ======================= K5: emit (recompute slots, dense out-write) =======================
__global__ __launch_bounds__(BLOCK) void k_emit(const int* __restrict__ idx,
                                                const int* __restrict__ off,
                                                const int* __restrict__ sliceBase,
                                                const int* __restrict__ blockOff,
                                                const float* __restrict__ val,
                                                float* __restrict__ out) {
    const int b = blockIdx.x, t = threadIdx.x, lane = t & 63, wave = t >> 6;
    const int4* p = (const int4*)(idx + (size_t)b * TILE2 + (size_t)t * EPT2);
    int v[EPT2];
#pragma unroll
    for (int j = 0; j < EPT2 / 4; ++j) {
        int4 q = p[j];
        v[4*j+0]=q.x; v[4*j+1]=q.y; v[4*j+2]=q.z; v[4*j+3]=q.w;
    }
    int tc[SLICES];
#pragma unroll
    for (int s = 0; s < SLICES; ++s) tc[s] = 0;
#pragma unroll
    for (int j = 0; j < EPT2; ++j) {
        unsigned s = (unsigned)v[j] >> SLICE_LG;
#pragma unroll
        for (int s2 = 0; s2 < SLICES; ++s2) tc[s2] += (s == (unsigned)s2);
    }
    int inc[SLICES];
#pragma unroll
    for (int s = 0; s < SLICES; ++s) inc[s] = tc[s];
#pragma unroll
    for (int d = 1; d < 64; d <<= 1) {
#pragma unroll
        for (int s = 0; s < SLICES; ++s) {
            int u = __shfl_up(inc[s], d);
            if (lane >= d) inc[s] += u;
        }
    }
    // scalar dest-rank scan
    int cnt = 0;
#pragma unroll
    for (int s = 0; s < SLICES; ++s) cnt += tc[s];
    int xinc = cnt;
#pragma unroll
    for (int d = 1; d < 64; d <<= 1) {
        int u = __shfl_up(xinc, d);
        if (lane >= d) xinc += u;
    }
    __shared__ int wtot[4][SLICES], wbase[4][SLICES];
    __shared__ int wsum[4], woff[4], sTot;
    if (lane == 63) {
#pragma unroll
        for (int s = 0; s < SLICES; ++s) wtot[wave][s] = inc[s];
        wsum[wave] = xinc;
    }
    __syncthreads();
    if (t == 0) {
        int run[SLICES];
#pragma unroll
        for (int s = 0; s < SLICES; ++s) run[s] = 0;
        for (int w = 0; w < 4; ++w)
#pragma unroll
            for (int s = 0; s < SLICES; ++s) { wbase[w][s] = run[s]; run[s] += wtot[w][s]; }
        int rs = 0;
        for (int w = 0; w < 4; ++w) { woff[w] = rs; rs += wsum[w]; }
        sTot = rs;
    }
    __syncthreads();
    __shared__ int exb[BLOCK][SLICES + 1];
#pragma unroll
    for (int s = 0; s < SLICES; ++s)
        exb[t][s] = sliceBase[s] + off[(size_t)b * SLICES + s]
                  + (inc[s] - tc[s]) + wbase[wave][s];
    // pass 1: slots (LDS RMW, no global deps)
    int slotA[EPT2];
#pragma unroll
    for (int j = 0; j < EPT2; ++j) {
        unsigned s = (unsigned)v[j] >> SLICE_LG;
        slotA[j] = (s < SLICES) ? exb[t][s]++ : 0;
    }
    // pass 2: 32 independent val gathers (block-local windows -> L1-hot)
    float tmp[EPT2];
#pragma unroll
    for (int j = 0; j < EPT2; ++j) tmp[j] = val[slotA[j]];
    // pass 3: LDS compact in dest order
    __shared__ float vals[TILE2];
    int o = (xinc - cnt) + woff[wave];
#pragma unroll
    for (int j = 0; j < EPT2; ++j)
        if (v[j] >= 0) vals[o++] = tmp[j];
    __syncthreads();
    const int base = blockOff[b];
    const int tot = sTot;
    for (int i = t; i < tot; i += BLOCK)
        __builtin_nontemporal_store(vals[i], out + base + i);
}

// ======================= K6: zero the tail =======================
__global__ __launch_bounds__(256) void k_tail(float* __restrict__ out,
                                              const int* __restrict__ total_p) {
    const int total = *total_p;
    const int i = (blockIdx.x * 256 + threadIdx.x) * 4;
    if (i >= total) {
        vfloat4 z = (vfloat4)(0.f);
        __builtin_nontemporal_store(z, (vfloat4*)(out + i));
    } else if (i + 4 > total) {
#pragma unroll
        for (int k = 0; k < 4; ++k)
            if (i + k >= total) out[i + k] = 0.f;
    }
}

// ======================= Fallback (R5) kernels =======================
__global__ __launch_bounds__(BLOCK) void k_reduce(const int* __restrict__ idx,
                                                  int* __restrict__ blockSums) {
    const int b = blockIdx.x, t = threadIdx.x;
    const int4* p = (const int4*)(idx + (size_t)b * TILE + (size_t)t * EPT);
    int cnt = 0;
#pragma unroll
    for (int j = 0; j < EPT / 4; ++j) {
        int4 v = p[j];
        cnt += (v.x >= 0) + (v.y >= 0) + (v.z >= 0) + (v.w >= 0);
    }
#pragma unroll
    for (int d = 32; d > 0; d >>= 1) cnt += __shfl_down(cnt, d);
    __shared__ int wsum[BLOCK / 64];
    const int lane = t & 63, wave = t >> 6;
    if (lane == 0) wsum[wave] = cnt;
    __syncthreads();
    if (t == 0) {
        int s = 0;
#pragma unroll
        for (int w = 0; w < BLOCK / 64; ++w) s += wsum[w];
        blockSums[b] = s;
    }
}

__global__ __launch_bounds__(256) void k_scan(const int* __restrict__ blockSums,
                                              int* __restrict__ blockOffsets) {
    const int t = threadIdx.x;
    const int lane = t & 63, wave = t >> 6;
    int vals[16];
    const int4* p = (const int4*)(blockSums + t * 16);
#pragma unroll
    for (int j = 0; j < 4; ++j) {
        int4 v = p[j];
        vals[4*j+0]=v.x; vals[4*j+1]=v.y; vals[4*j+2]=v.z; vals[4*j+3]=v.w;
    }
    int tsum = 0;
#pragma unroll
    for (int j = 0; j < 16; ++j) tsum += vals[j];
    int x = tsum;
#pragma unroll
    for (int d = 1; d < 64; d <<= 1) {
        int y = __shfl_up(x, d);
        if (lane >= d) x += y;
    }
    __shared__ int wsum[4], woff[4];
    if (lane == 63) wsum[wave] = x;
    __syncthreads();
    if (t == 0) {
        int s = 0;
#pragma unroll
        for (int w = 0; w < 4; ++w) { woff[w] = s; s += wsum[w]; }
        blockOffsets[NBLOCKS] = s;
    }
    __syncthreads();
    int run = (x - tsum) + woff[wave];
#pragma unroll
    for (int j = 0; j < 16; ++j) {
        blockOffsets[t * 16 + j] = run;
        run += vals[j];
    }
}

__global__ __launch_bounds__(BLOCK) void k_scatter(const int* __restrict__ idx,
                                                   const float* __restrict__ src,
                                                   const int* __restrict__ blockOffsets,
                                                   float* __restrict__ out) {
    const int b = blockIdx.x, t = threadIdx.x;
    const int lane = t & 63, wave = t >> 6;
    const int4* p = (const int4*)(idx + (size_t)b * TILE2 + (size_t)t * EPT2);
    int v[EPT2];
#pragma unroll
    for (int j = 0; j < EPT2 / 4; ++j) {
        int4 q = p[j];
        v[4*j+0]=q.x; v[4*j+1]=q.y; v[4*j+2]=q.z; v[4*j+3]=q.w;
    }
    int cnt = 0;
#pragma unroll
    for (int j = 0; j < EPT2; ++j) cnt += (v[j] >= 0);
    int x = cnt;
#pragma unroll
    for (int d = 1; d < 64; d <<= 1) {
        int y = __shfl_up(x, d);
        if (lane >= d) x += y;
    }
    __shared__ int wsum[BLOCK / 64], woff[BLOCK / 64];
    __shared__ int btotal;
    if (lane == 63) wsum[wave] = x;
    __syncthreads();
    if (t == 0) {
        int s = 0;
#pragma unroll
        for (int w = 0; w < BLOCK / 64; ++w) { woff[w] = s; s += wsum[w]; }
        btotal = s;
    }
    __syncthreads();
    const int off0 = (x - cnt) + woff[wave];
    __shared__ float vals[TILE2];
#pragma unroll 1
    for (int s = 0; s < SLICES5; ++s) {
        float tmp[EPT2];
#pragma unroll
        for (int j = 0; j < EPT2; ++j) {
            const bool m = (int)((unsigned)v[j] >> SLICE_LG5) == s;
            tmp[j] = src[m ? v[j] : 0];
        }
        asm volatile("s_waitcnt vmcnt(0)" ::: "memory");
        int o = off0;
#pragma unroll
        for (int j = 0; j < EPT2; ++j) {
            const bool acc = v[j] >= 0;
            const bool m = (int)((unsigned)v[j] >> SLICE_LG5) == s;
            if (m) vals[o] = tmp[j];
            o += acc;
        }
    }
    __syncthreads();
    const int base = blockOffsets[2 * b];
    const int tot  = btotal;
    for (int i = t; i < tot; i += BLOCK)
        __builtin_nontemporal_store(vals[i], out + base + i);
}

// ======================= host =======================
extern "C" void kernel_launch(void* const* d_in, const int* in_sizes, int n_in,
                              void* d_out, int out_size, void* d_ws, size_t ws_size,
                              hipStream_t stream) {
    const int*   idx = (const int*)d_in[0];
    const float* src = (const float*)d_in[1];
    float*       out = (float*)d_out;

    // binned-path workspace layout (ints)
    int* cnt       = (int*)d_ws;                 // NB2*16 = 32768
    int* off       = cnt + NB2 * SLICES;         // 32768
    int* sliceBase = off + NB2 * SLICES;         // 17
    int* blockOff  = sliceBase + (SLICES + 1);   // NB2+1 = 2049
    int* bins      = blockOff + (NB2 + 1);       // N ints
    float* val     = (float*)(bins + N_TOTAL);   // N floats
    const size_t need = ((size_t)(2 * NB2 * SLICES + SLICES + 1 + NB2 + 1)
                         + 2ull * N_TOTAL) * 4ull;

    if (ws_size >= need) {
        k_count <<<NB2, BLOCK, 0, stream>>>(idx, cnt);
        k_scan2 <<<1, BLOCK, 0, stream>>>(cnt, off, sliceBase, blockOff);
        k_bin   <<<NB2, BLOCK, 0, stream>>>(idx, off, sliceBase, bins);
        k_gather<<<NB2, BLOCK, 0, stream>>>(bins, src, sliceBase, val);
        k_emit  <<<NB2, BLOCK, 0, stream>>>(idx, off, sliceBase, blockOff, val, out);
        k_tail  <<<N_TOTAL / 4 / 256, 256, 0, stream>>>(out, blockOff + NB2);
    } else {
        int* blockSums    = (int*)d_ws;
        int* blockOffsets = blockSums + NBLOCKS;
        k_reduce <<<NBLOCKS, BLOCK, 0, stream>>>(idx, blockSums);
        k_scan   <<<1, 256, 0, stream>>>(blockSums, blockOffsets);
        k_scatter<<<NB2, BLOCK, 0, stream>>>(idx, src, blockOffsets, out);
        k_tail   <<<N_TOTAL / 4 / 256, 256, 0, stream>>>(out, blockOffsets + NBLOCKS);
    }
}

// Round 7
// 367.657 us; speedup vs baseline: 1.0041x; 1.0041x over previous
//
#include <hip/hip_runtime.h>

// Stream compaction via slice-binning (R7).
//   mask[i] = accept_index[i] >= 0 ; dst = excl-scan(mask)
//   out[dst[i]] = src[accept_index[i]] ; out[total..N) = 0
//
// R6 post-mortem: binning works (gather src fetch 160MB vs R5's 640MB) but
// the LDS occupancy pad was compiler-eliminated -> 66% occupancy -> all
// generations live -> 8MB/XCD working set in 4MB L2 -> 2.5x src fetch.
// R7: persistent gather - exactly 512 blocks (2/CU), each loops its 4
// generations internally. Residency is guaranteed by the launch shape; at any
// instant XCD x (= blockIdx%8, round-robin heuristic) works ONE 4MB slice
// that exactly fits its L2. k_count: register histogram (no LDS atomics).
//
// Pipeline: K1 count -> K2 scan -> K3 bin -> K4 gather -> K5 emit -> K6 tail.
// Falls back to the R5 single-kernel path if ws_size < ~135 MB.

#define N_TOTAL  16777216
#define BLOCK    256
#define EPT2     32
#define TILE2    (BLOCK * EPT2)        // 8192
#define NB2      (N_TOTAL / TILE2)     // 2048
#define SLICE_LG 20                    // 2^20 elements = 4 MB slice
#define SLICES   16
#define GBLOCKS  512                   // persistent gather blocks (2/CU)

// fallback (R5) tiling
#define EPT      16
#define TILE     (BLOCK * EPT)         // 4096
#define NBLOCKS  (N_TOTAL / TILE)      // 4096
#define SLICE_LG5 22
#define SLICES5  (N_TOTAL >> SLICE_LG5)

typedef float vfloat4 __attribute__((ext_vector_type(4)));

// ======================= K1: per-block per-slice counts =======================
__global__ __launch_bounds__(BLOCK) void k_count(const int* __restrict__ idx,
                                                 int* __restrict__ cnt) {
    const int b = blockIdx.x, t = threadIdx.x, lane = t & 63, wave = t >> 6;
    const int4* p = (const int4*)(idx + (size_t)b * TILE2 + (size_t)t * EPT2);
    int v[EPT2];
#pragma unroll
    for (int j = 0; j < EPT2 / 4; ++j) {
        int4 q = p[j];
        v[4*j+0]=q.x; v[4*j+1]=q.y; v[4*j+2]=q.z; v[4*j+3]=q.w;
    }
    int tc[SLICES];
#pragma unroll
    for (int s = 0; s < SLICES; ++s) tc[s] = 0;
#pragma unroll
    for (int j = 0; j < EPT2; ++j) {
        unsigned s = (unsigned)v[j] >> SLICE_LG;
#pragma unroll
        for (int s2 = 0; s2 < SLICES; ++s2) tc[s2] += (s == (unsigned)s2);
    }
#pragma unroll
    for (int s = 0; s < SLICES; ++s)
#pragma unroll
        for (int d = 32; d > 0; d >>= 1) tc[s] += __shfl_down(tc[s], d);
    __shared__ int ws[4][SLICES];
    if (lane == 0)
#pragma unroll
        for (int s = 0; s < SLICES; ++s) ws[wave][s] = tc[s];
    __syncthreads();
    if (t < SLICES)
        cnt[b * SLICES + t] = ws[0][t] + ws[1][t] + ws[2][t] + ws[3][t];
}

// ======================= K2: scan (dest offsets + slice-column offsets) =======================
// cnt[NB2][16] -> off[NB2][16] (exclusive within each slice column),
// sliceBase[17], blockOff[NB2+1] (blockOff[NB2] = grand total).
__global__ __launch_bounds__(BLOCK) void k_scan2(const int* __restrict__ cnt,
                                                 int* __restrict__ off,
                                                 int* __restrict__ sliceBase,
                                                 int* __restrict__ blockOff) {
    const int t = threadIdx.x, lane = t & 63, wave = t >> 6;
    const int R = NB2 / BLOCK;   // 8 rows per thread, contiguous
    int sum[SLICES];
#pragma unroll
    for (int s = 0; s < SLICES; ++s) sum[s] = 0;
    for (int r = 0; r < R; ++r) {
        const int4* row = (const int4*)(cnt + (size_t)(t * R + r) * SLICES);
        int4 c0 = row[0], c1 = row[1], c2 = row[2], c3 = row[3];
        sum[0]+=c0.x; sum[1]+=c0.y; sum[2]+=c0.z; sum[3]+=c0.w;
        sum[4]+=c1.x; sum[5]+=c1.y; sum[6]+=c1.z; sum[7]+=c1.w;
        sum[8]+=c2.x; sum[9]+=c2.y; sum[10]+=c2.z; sum[11]+=c2.w;
        sum[12]+=c3.x; sum[13]+=c3.y; sum[14]+=c3.z; sum[15]+=c3.w;
    }
    int inc[SLICES];
#pragma unroll
    for (int s = 0; s < SLICES; ++s) inc[s] = sum[s];
#pragma unroll
    for (int d = 1; d < 64; d <<= 1) {
#pragma unroll
        for (int s = 0; s < SLICES; ++s) {
            int u = __shfl_up(inc[s], d);
            if (lane >= d) inc[s] += u;
        }
    }
    int tTot = 0;
#pragma unroll
    for (int s = 0; s < SLICES; ++s) tTot += sum[s];
    int tInc = tTot;
#pragma unroll
    for (int d = 1; d < 64; d <<= 1) {
        int u = __shfl_up(tInc, d);
        if (lane >= d) tInc += u;
    }
    __shared__ int wtot[4][SLICES], wstot[4];
    __shared__ int wbase[4][SLICES], wsbase[4];
    if (lane == 63) {
#pragma unroll
        for (int s = 0; s < SLICES; ++s) wtot[wave][s] = inc[s];
        wstot[wave] = tInc;
    }
    __syncthreads();
    if (t == 0) {
        int run[SLICES];
#pragma unroll
        for (int s = 0; s < SLICES; ++s) run[s] = 0;
        for (int w = 0; w < 4; ++w)
#pragma unroll
            for (int s = 0; s < SLICES; ++s) { wbase[w][s] = run[s]; run[s] += wtot[w][s]; }
        int sr = 0;
#pragma unroll
        for (int s = 0; s < SLICES; ++s) { sliceBase[s] = sr; sr += run[s]; }
        sliceBase[SLICES] = sr;
        blockOff[NB2] = sr;
        int rs = 0;
        for (int w = 0; w < 4; ++w) { wsbase[w] = rs; rs += wstot[w]; }
    }
    __syncthreads();
    int ex[SLICES];
#pragma unroll
    for (int s = 0; s < SLICES; ++s) ex[s] = inc[s] - sum[s] + wbase[wave][s];
    int exA = tInc - tTot + wsbase[wave];
    for (int r = 0; r < R; ++r) {
        const int b = t * R + r;
        blockOff[b] = exA;
        const int4* row = (const int4*)(cnt + (size_t)b * SLICES);
        int4 c0 = row[0], c1 = row[1], c2 = row[2], c3 = row[3];
        int rv[SLICES] = {c0.x,c0.y,c0.z,c0.w, c1.x,c1.y,c1.z,c1.w,
                          c2.x,c2.y,c2.z,c2.w, c3.x,c3.y,c3.z,c3.w};
#pragma unroll
        for (int s = 0; s < SLICES; ++s) {
            off[(size_t)b * SLICES + s] = ex[s];
            ex[s] += rv[s];
            exA   += rv[s];
        }
    }
}

// ======================= K3: bin table-indices by slice =======================
__global__ __launch_bounds__(BLOCK) void k_bin(const int* __restrict__ idx,
                                               const int* __restrict__ off,
                                               const int* __restrict__ sliceBase,
                                               int* __restrict__ bins) {
    const int b = blockIdx.x, t = threadIdx.x, lane = t & 63, wave = t >> 6;
    const int4* p = (const int4*)(idx + (size_t)b * TILE2 + (size_t)t * EPT2);
    int v[EPT2];
#pragma unroll
    for (int j = 0; j < EPT2 / 4; ++j) {
        int4 q = p[j];
        v[4*j+0]=q.x; v[4*j+1]=q.y; v[4*j+2]=q.z; v[4*j+3]=q.w;
    }
    int tc[SLICES];
#pragma unroll
    for (int s = 0; s < SLICES; ++s) tc[s] = 0;
#pragma unroll
    for (int j = 0; j < EPT2; ++j) {
        unsigned s = (unsigned)v[j] >> SLICE_LG;
#pragma unroll
        for (int s2 = 0; s2 < SLICES; ++s2) tc[s2] += (s == (unsigned)s2);
    }
    int inc[SLICES];
#pragma unroll
    for (int s = 0; s < SLICES; ++s) inc[s] = tc[s];
#pragma unroll
    for (int d = 1; d < 64; d <<= 1) {
#pragma unroll
        for (int s = 0; s < SLICES; ++s) {
            int u = __shfl_up(inc[s], d);
            if (lane >= d) inc[s] += u;
        }
    }
    __shared__ int wtot[4][SLICES], wbase[4][SLICES];
    __shared__ int gbase[SLICES], segStart[SLICES + 1];
    if (lane == 63)
#pragma unroll
        for (int s = 0; s < SLICES; ++s) wtot[wave][s] = inc[s];
    __syncthreads();
    if (t == 0) {
        int run[SLICES];
#pragma unroll
        for (int s = 0; s < SLICES; ++s) run[s] = 0;
        for (int w = 0; w < 4; ++w)
#pragma unroll
            for (int s = 0; s < SLICES; ++s) { wbase[w][s] = run[s]; run[s] += wtot[w][s]; }
        int sr = 0;
#pragma unroll
        for (int s = 0; s < SLICES; ++s) { segStart[s] = sr; sr += run[s]; }
        segStart[SLICES] = sr;
#pragma unroll
        for (int s = 0; s < SLICES; ++s)
            gbase[s] = sliceBase[s] + off[(size_t)b * SLICES + s] - segStart[s];
    }
    __syncthreads();
    __shared__ int exb[BLOCK][SLICES + 1];   // +1 pad vs 32 banks
    __shared__ int binsBuf[TILE2];
#pragma unroll
    for (int s = 0; s < SLICES; ++s)
        exb[t][s] = segStart[s] + (inc[s] - tc[s]) + wbase[wave][s];
#pragma unroll
    for (int j = 0; j < EPT2; ++j) {
        unsigned s = (unsigned)v[j] >> SLICE_LG;
        if (s < SLICES) {
            int pLoc = exb[t][s]++;
            binsBuf[pLoc] = v[j];
        }
    }
    __syncthreads();
    const int tot = segStart[SLICES];
    for (int k = t; k < tot; k += BLOCK) {
        int x = binsBuf[k];
        int s = 0;
#pragma unroll
        for (int q = 1; q < SLICES; ++q) s += (k >= segStart[q]);
        __builtin_nontemporal_store(x, bins + gbase[s] + k);
    }
}

// ======================= K4: persistent per-slice dense gather =======================
// Exactly 512 blocks (2/CU) -> all resident from dispatch. Block n: XCD n&7
// (round-robin heuristic, speed-only), rank q. Each block loops 4 generations:
// gens 0,1 -> slice 2x (chunks q, 64+q), gens 2,3 -> slice 2x+1. Per-XCD live
// working set = one 4MB slice = its L2.
__global__ __launch_bounds__(BLOCK) void k_gather(const int* __restrict__ bins,
                                                  const float* __restrict__ src,
                                                  const int* __restrict__ sliceBase,
                                                  float* __restrict__ val) {
    const int t = threadIdx.x;
    const int n = blockIdx.x;          // 0..511
    const int x = n & 7;               // hoped XCD
    const int q = (n >> 3) & 63;       // rank within XCD
#pragma unroll 1
    for (int g = 0; g < 4; ++g) {
        const int s = 2 * x + (g >> 1);
        const int c = (g & 1) * 64 + q;    // chunk 0..127 within slice
        const int s0 = sliceBase[s], s1 = sliceBase[s + 1];
        const int len = s1 - s0;
        const int L = (len + 127) >> 7;
        const int start = s0 + c * L;
        const int end = (start + L < s1) ? (start + L) : s1;
        for (int k0 = start + t; k0 < end; k0 += BLOCK * 8) {
            int kk[8], bm[8];
            float fm[8];
#pragma unroll
            for (int m = 0; m < 8; ++m) kk[m] = k0 + m * BLOCK;
#pragma unroll
            for (int m = 0; m < 8; ++m) {
                int kc = kk[m] < end ? kk[m] : end - 1;
                bm[m] = __builtin_nontemporal_load(bins + kc);   // bins: stream once
            }
#pragma unroll
            for (int m = 0; m < 8; ++m) fm[m] = src[bm[m]];      // L2-resident slice
#pragma unroll
            for (int m = 0; m < 8; ++m)
                if (kk[m] < end) __builtin_nontemporal_store(fm[m], val + kk[m]);
        }
    }
}

// ======================= K5: emit (recompute slots, dense out-write) =======================
__global__ __launch_bounds__(BLOCK) void k_emit(const int* __restrict__ idx,
                                                const int* __restrict__ off,
                                                const int* __restrict__ sliceBase,
                                                const int* __restrict__ blockOff,
                                                const float* __restrict__ val,
                                                float* __restrict__ out) {
    const int b = blockIdx.x, t = threadIdx.x, lane = t & 63, wave = t >> 6;
    const int4* p = (const int4*)(idx + (size_t)b * TILE2 + (size_t)t * EPT2);
    int v[EPT2];
#pragma unroll
    for (int j = 0; j < EPT2 / 4; ++j) {
        int4 q = p[j];
        v[4*j+0]=q.x; v[4*j+1]=q.y; v[4*j+2]=q.z; v[4*j+3]=q.w;
    }
    int tc[SLICES];
#pragma unroll
    for (int s = 0; s < SLICES; ++s) tc[s] = 0;
#pragma unroll
    for (int j = 0; j < EPT2; ++j) {
        unsigned s = (unsigned)v[j] >> SLICE_LG;
#pragma unroll
        for (int s2 = 0; s2 < SLICES; ++s2) tc[s2] += (s == (unsigned)s2);
    }
    int inc[SLICES];
#pragma unroll
    for (int s = 0; s < SLICES; ++s) inc[s] = tc[s];
#pragma unroll
    for (int d = 1; d < 64; d <<= 1) {
#pragma unroll
        for (int s = 0; s < SLICES; ++s) {
            int u = __shfl_up(inc[s], d);
            if (lane >= d) inc[s] += u;
        }
    }
    // scalar dest-rank scan
    int cnt = 0;
#pragma unroll
    for (int s = 0; s < SLICES; ++s) cnt += tc[s];
    int xinc = cnt;
#pragma unroll
    for (int d = 1; d < 64; d <<= 1) {
        int u = __shfl_up(xinc, d);
        if (lane >= d) xinc += u;
    }
    __shared__ int wtot[4][SLICES], wbase[4][SLICES];
    __shared__ int wsum[4], woff[4], sTot;
    if (lane == 63) {
#pragma unroll
        for (int s = 0; s < SLICES; ++s) wtot[wave][s] = inc[s];
        wsum[wave] = xinc;
    }
    __syncthreads();
    if (t == 0) {
        int run[SLICES];
#pragma unroll
        for (int s = 0; s < SLICES; ++s) run[s] = 0;
        for (int w = 0; w < 4; ++w)
#pragma unroll
            for (int s = 0; s < SLICES; ++s) { wbase[w][s] = run[s]; run[s] += wtot[w][s]; }
        int rs = 0;
        for (int w = 0; w < 4; ++w) { woff[w] = rs; rs += wsum[w]; }
        sTot = rs;
    }
    __syncthreads();
    __shared__ int exb[BLOCK][SLICES + 1];
#pragma unroll
    for (int s = 0; s < SLICES; ++s)
        exb[t][s] = sliceBase[s] + off[(size_t)b * SLICES + s]
                  + (inc[s] - tc[s]) + wbase[wave][s];
    // pass 1: slots (LDS RMW, no global deps)
    int slotA[EPT2];
#pragma unroll
    for (int j = 0; j < EPT2; ++j) {
        unsigned s = (unsigned)v[j] >> SLICE_LG;
        slotA[j] = (s < SLICES) ? exb[t][s]++ : 0;
    }
    // pass 2: 32 independent val gathers (block-local windows -> L1-hot)
    float tmp[EPT2];
#pragma unroll
    for (int j = 0; j < EPT2; ++j) tmp[j] = val[slotA[j]];
    // pass 3: LDS compact in dest order
    __shared__ float vals[TILE2];
    int o = (xinc - cnt) + woff[wave];
#pragma unroll
    for (int j = 0; j < EPT2; ++j)
        if (v[j] >= 0) vals[o++] = tmp[j];
    __syncthreads();
    const int base = blockOff[b];
    const int tot = sTot;
    for (int i = t; i < tot; i += BLOCK)
        __builtin_nontemporal_store(vals[i], out + base + i);
}

// ======================= K6: zero the tail =======================
__global__ __launch_bounds__(256) void k_tail(float* __restrict__ out,
                                              const int* __restrict__ total_p) {
    const int total = *total_p;
    const int i = (blockIdx.x * 256 + threadIdx.x) * 4;
    if (i >= total) {
        vfloat4 z = (vfloat4)(0.f);
        __builtin_nontemporal_store(z, (vfloat4*)(out + i));
    } else if (i + 4 > total) {
#pragma unroll
        for (int k = 0; k < 4; ++k)
            if (i + k >= total) out[i + k] = 0.f;
    }
}

// ======================= Fallback (R5) kernels =======================
__global__ __launch_bounds__(BLOCK) void k_reduce(const int* __restrict__ idx,
                                                  int* __restrict__ blockSums) {
    const int b = blockIdx.x, t = threadIdx.x;
    const int4* p = (const int4*)(idx + (size_t)b * TILE + (size_t)t * EPT);
    int cnt = 0;
#pragma unroll
    for (int j = 0; j < EPT / 4; ++j) {
        int4 v = p[j];
        cnt += (v.x >= 0) + (v.y >= 0) + (v.z >= 0) + (v.w >= 0);
    }
#pragma unroll
    for (int d = 32; d > 0; d >>= 1) cnt += __shfl_down(cnt, d);
    __shared__ int wsum[BLOCK / 64];
    const int lane = t & 63, wave = t >> 6;
    if (lane == 0) wsum[wave] = cnt;
    __syncthreads();
    if (t == 0) {
        int s = 0;
#pragma unroll
        for (int w = 0; w < BLOCK / 64; ++w) s += wsum[w];
        blockSums[b] = s;
    }
}

__global__ __launch_bounds__(256) void k_scan(const int* __restrict__ blockSums,
                                              int* __restrict__ blockOffsets) {
    const int t = threadIdx.x;
    const int lane = t & 63, wave = t >> 6;
    int vals[16];
    const int4* p = (const int4*)(blockSums + t * 16);
#pragma unroll
    for (int j = 0; j < 4; ++j) {
        int4 v = p[j];
        vals[4*j+0]=v.x; vals[4*j+1]=v.y; vals[4*j+2]=v.z; vals[4*j+3]=v.w;
    }
    int tsum = 0;
#pragma unroll
    for (int j = 0; j < 16; ++j) tsum += vals[j];
    int x = tsum;
#pragma unroll
    for (int d = 1; d < 64; d <<= 1) {
        int y = __shfl_up(x, d);
        if (lane >= d) x += y;
    }
    __shared__ int wsum[4], woff[4];
    if (lane == 63) wsum[wave] = x;
    __syncthreads();
    if (t == 0) {
        int s = 0;
#pragma unroll
        for (int w = 0; w < 4; ++w) { woff[w] = s; s += wsum[w]; }
        blockOffsets[NBLOCKS] = s;
    }
    __syncthreads();
    int run = (x - tsum) + woff[wave];
#pragma unroll
    for (int j = 0; j < 16; ++j) {
        blockOffsets[t * 16 + j] = run;
        run += vals[j];
    }
}

__global__ __launch_bounds__(BLOCK) void k_scatter(const int* __restrict__ idx,
                                                   const float* __restrict__ src,
                                                   const int* __restrict__ blockOffsets,
                                                   float* __restrict__ out) {
    const int b = blockIdx.x, t = threadIdx.x;
    const int lane = t & 63, wave = t >> 6;
    const int4* p = (const int4*)(idx + (size_t)b * TILE2 + (size_t)t * EPT2);
    int v[EPT2];
#pragma unroll
    for (int j = 0; j < EPT2 / 4; ++j) {
        int4 q = p[j];
        v[4*j+0]=q.x; v[4*j+1]=q.y; v[4*j+2]=q.z; v[4*j+3]=q.w;
    }
    int cnt = 0;
#pragma unroll
    for (int j = 0; j < EPT2; ++j) cnt += (v[j] >= 0);
    int x = cnt;
#pragma unroll
    for (int d = 1; d < 64; d <<= 1) {
        int y = __shfl_up(x, d);
        if (lane >= d) x += y;
    }
    __shared__ int wsum[BLOCK / 64], woff[BLOCK / 64];
    __shared__ int btotal;
    if (lane == 63) wsum[wave] = x;
    __syncthreads();
    if (t == 0) {
        int s = 0;
#pragma unroll
        for (int w = 0; w < BLOCK / 64; ++w) { woff[w] = s; s += wsum[w]; }
        btotal = s;
    }
    __syncthreads();
    const int off0 = (x - cnt) + woff[wave];
    __shared__ float vals[TILE2];
#pragma unroll 1
    for (int s = 0; s < SLICES5; ++s) {
        float tmp[EPT2];
#pragma unroll
        for (int j = 0; j < EPT2; ++j) {
            const bool m = (int)((unsigned)v[j] >> SLICE_LG5) == s;
            tmp[j] = src[m ? v[j] : 0];
        }
        asm volatile("s_waitcnt vmcnt(0)" ::: "memory");
        int o = off0;
#pragma unroll
        for (int j = 0; j < EPT2; ++j) {
            const bool acc = v[j] >= 0;
            const bool m = (int)((unsigned)v[j] >> SLICE_LG5) == s;
            if (m) vals[o] = tmp[j];
            o += acc;
        }
    }
    __syncthreads();
    const int base = blockOffsets[2 * b];
    const int tot  = btotal;
    for (int i = t; i < tot; i += BLOCK)
        __builtin_nontemporal_store(vals[i], out + base + i);
}

// ======================= host =======================
extern "C" void kernel_launch(void* const* d_in, const int* in_sizes, int n_in,
                              void* d_out, int out_size, void* d_ws, size_t ws_size,
                              hipStream_t stream) {
    const int*   idx = (const int*)d_in[0];
    const float* src = (const float*)d_in[1];
    float*       out = (float*)d_out;

    // binned-path workspace layout (ints)
    int* cnt       = (int*)d_ws;                 // NB2*16 = 32768
    int* off       = cnt + NB2 * SLICES;         // 32768
    int* sliceBase = off + NB2 * SLICES;         // 17
    int* blockOff  = sliceBase + (SLICES + 1);   // NB2+1 = 2049
    int* bins      = blockOff + (NB2 + 1);       // N ints
    float* val     = (float*)(bins + N_TOTAL);   // N floats
    const size_t need = ((size_t)(2 * NB2 * SLICES + SLICES + 1 + NB2 + 1)
                         + 2ull * N_TOTAL) * 4ull;

    if (ws_size >= need) {
        k_count <<<NB2, BLOCK, 0, stream>>>(idx, cnt);
        k_scan2 <<<1, BLOCK, 0, stream>>>(cnt, off, sliceBase, blockOff);
        k_bin   <<<NB2, BLOCK, 0, stream>>>(idx, off, sliceBase, bins);
        k_gather<<<GBLOCKS, BLOCK, 0, stream>>>(bins, src, sliceBase, val);
        k_emit  <<<NB2, BLOCK, 0, stream>>>(idx, off, sliceBase, blockOff, val, out);
        k_tail  <<<N_TOTAL / 4 / 256, 256, 0, stream>>>(out, blockOff + NB2);
    } else {
        int* blockSums    = (int*)d_ws;
        int* blockOffsets = blockSums + NBLOCKS;
        k_reduce <<<NBLOCKS, BLOCK, 0, stream>>>(idx, blockSums);
        k_scan   <<<1, 256, 0, stream>>>(blockSums, blockOffsets);
        k_scatter<<<NB2, BLOCK, 0, stream>>>(idx, src, blockOffsets, out);
        k_tail   <<<N_TOTAL / 4 / 256, 256, 0, stream>>>(out, blockOffsets + NBLOCKS);
    }
}